// Round 6
// baseline (1686.452 us; speedup 1.0000x reference)
//
#include <hip/hip_runtime.h>
#include <stdint.h>

#define N_UPDATE 3
#define HD 32
#define FN 16

typedef unsigned short u16;
typedef __bf16 bf16x8 __attribute__((ext_vector_type(8)));
typedef float f32x4 __attribute__((ext_vector_type(4)));

__device__ __forceinline__ float bf2f(u16 u) {
  union { uint32_t i; float f; } v; v.i = ((uint32_t)u) << 16; return v.f;
}
__device__ __forceinline__ u16 f2bf(float f) {
  union { uint32_t i; float f; } v; v.f = f;
  uint32_t x = v.i;
  return (u16)((x + 0x7fffu + ((x >> 16) & 1u)) >> 16);  // RNE
}

union frag16 { uint4 v; bf16x8 b; u16 s[8]; };

__global__ void k_zero_i(int* __restrict__ p, int n) {
  int i = blockIdx.x * blockDim.x + threadIdx.x;
  if (i < n) p[i] = 0;
}

// ---------------- both histograms in one pass
__global__ void k_hist2(const int* __restrict__ eidx, int* __restrict__ cntS,
                        int* __restrict__ cntD, int E) {
  int e = blockIdx.x * blockDim.x + threadIdx.x;
  if (e >= E) return;
  int2 sd = ((const int2*)eidx)[e];
  atomicAdd(&cntS[sd.x], 1);
  atomicAdd(&cntD[sd.y], 1);
}

// ---------------- single-block exclusive scan; writes out1[0..N] (and out2 if non-null)
__global__ __launch_bounds__(1024) void k_scan(const int* __restrict__ cnt,
                                               int* __restrict__ out1,
                                               int* __restrict__ out2, int N) {
  __shared__ int sums[1024];
  int chunk = (N + 1023) / 1024;
  int beg = threadIdx.x * chunk;
  int end = beg + chunk; if (end > N) end = N;
  if (beg > N) beg = N;
  int s = 0;
  for (int i = beg; i < end; i++) s += cnt[i];
  sums[threadIdx.x] = s;
  __syncthreads();
  for (int off = 1; off < 1024; off <<= 1) {
    int v = (threadIdx.x >= off) ? sums[threadIdx.x - off] : 0;
    __syncthreads();
    sums[threadIdx.x] += v;
    __syncthreads();
  }
  int run = (threadIdx.x == 0) ? 0 : sums[threadIdx.x - 1];
  for (int i = beg; i < end; i++) {
    out1[i] = run;
    if (out2) out2[i] = run;
    run += cnt[i];
  }
  if (end == N) {  // tail threads all hold run == total
    out1[N] = run;
    if (out2) out2[N] = run;
  }
}

// ---------------- scatter into src-sorted order
__global__ void k_scatter_src(const int* __restrict__ eidx, int* __restrict__ ptrS,
                              int* __restrict__ se_src, int* __restrict__ se_dst,
                              int* __restrict__ invp, int E) {
  int e = blockIdx.x * blockDim.x + threadIdx.x;
  if (e >= E) return;
  int2 sd = ((const int2*)eidx)[e];
  int pos = atomicAdd(&ptrS[sd.x], 1);
  se_src[pos] = sd.x;
  se_dst[pos] = sd.y;
  invp[e] = pos;
}

// ---------------- dst-order rank for each src-sorted edge
__global__ void k_dstpos(const int* __restrict__ se_dst, int* __restrict__ ptrD,
                         int* __restrict__ dstpos, int E) {
  int q = blockIdx.x * blockDim.x + threadIdx.x;
  if (q >= E) return;
  dstpos[q] = atomicAdd(&ptrD[se_dst[q]], 1);
}

// ---------------- Bf[t][lane]: MFMA B-fragments, 128 tiles (2 passes x 64).
// pass p, tile t2, col c: j2=t2*16+c, o_l=j2>>6, k=j2&63, o=p*16+o_l
// B[h][j2] = Wm2[k*1024 + h*32 + o]
__global__ void k_prep_bf(const float* __restrict__ Wm2, uint4* __restrict__ Bf) {
  int t = blockIdx.x;       // 128
  int lane = threadIdx.x;   // 64
  int col = lane & 15;
  int hg = lane >> 4;
  int p = t >> 6;
  int t2 = t & 63;
  int j2 = t2 * 16 + col;
  int o = p * 16 + (j2 >> 6);
  int k = j2 & 63;
  frag16 f;
#pragma unroll
  for (int jj = 0; jj < 8; jj++) {
    int h = hg * 8 + jj;
    f.s[jj] = f2bf(Wm2[k * 1024 + h * 32 + o]);
  }
  Bf[t * 64 + lane] = f.v;
}

// ---------------- h0 init + hb = h0 @ bm2
__global__ void k_init_h(const float* __restrict__ x, const float* __restrict__ bm2,
                         float* __restrict__ h, float* __restrict__ hbbuf, int N) {
  int idx = blockIdx.x * blockDim.x + threadIdx.x;
  if (idx >= N * HD) return;
  int n = idx >> 5, o = idx & 31;
  float v = (o < FN) ? x[n * FN + o] : 0.f;
  h[idx] = v;
  float hb = 0.f;
#pragma unroll
  for (int k = 0; k < 32; k++)
    hb = fmaf(__shfl(v, k, 32), bm2[k * 32 + o], hb);
  hbbuf[idx] = hb;
}

// ---------------- edge MLP -> ee bf16 [E][64], written at sorted position invp[e]
__global__ __launch_bounds__(256) void k_edge_mlp(
    const float* __restrict__ ea,
    const float* __restrict__ Wm0, const float* __restrict__ bm0,
    const float* __restrict__ Wm1, const float* __restrict__ bm1,
    const int* __restrict__ invp, u16* __restrict__ ee, int E) {
  int e = blockIdx.x * blockDim.x + threadIdx.x;
  if (e >= E) return;
  float a[16];
  {
    const float4* p = (const float4*)(ea + (size_t)e * 16);
    float4 v0 = p[0], v1 = p[1], v2 = p[2], v3 = p[3];
    a[0]=v0.x; a[1]=v0.y; a[2]=v0.z; a[3]=v0.w;
    a[4]=v1.x; a[5]=v1.y; a[6]=v1.z; a[7]=v1.w;
    a[8]=v2.x; a[9]=v2.y; a[10]=v2.z; a[11]=v2.w;
    a[12]=v3.x; a[13]=v3.y; a[14]=v3.z; a[15]=v3.w;
  }
  float t0[64];
#pragma unroll
  for (int j = 0; j < 64; j++) t0[j] = bm0[j];
#pragma unroll
  for (int k = 0; k < 16; k++) {
    float av = a[k];
#pragma unroll
    for (int j = 0; j < 64; j++) t0[j] = fmaf(av, Wm0[k * 64 + j], t0[j]);
  }
#pragma unroll
  for (int j = 0; j < 64; j++) t0[j] = fmaxf(t0[j], 0.f);

  u16* dst = ee + (size_t)invp[e] * 64;
#pragma unroll
  for (int half = 0; half < 2; half++) {
    float t1[32];
#pragma unroll
    for (int j = 0; j < 32; j++) t1[j] = bm1[half * 32 + j];
#pragma unroll
    for (int k = 0; k < 64; k++) {
      float tv = t0[k];
#pragma unroll
      for (int j = 0; j < 32; j++) t1[j] = fmaf(tv, Wm1[k * 64 + half * 32 + j], t1[j]);
    }
    unsigned int out[16];
#pragma unroll
    for (int j = 0; j < 16; j++) {
      u16 lo = f2bf(fmaxf(t1[2 * j], 0.f));
      u16 hi = f2bf(fmaxf(t1[2 * j + 1], 0.f));
      out[j] = (unsigned int)lo | ((unsigned int)hi << 16);
    }
    uint4* op = (uint4*)(dst + half * 32);
#pragma unroll
    for (int q = 0; q < 4; q++) {
      uint4 w; w.x = out[q*4+0]; w.y = out[q*4+1]; w.z = out[q*4+2]; w.w = out[q*4+3];
      op[q] = w;
    }
  }
}

// ---------------- G GEMM pass p: Gb[n][j2], j2 = o_l*64+k (o = p*16+o_l)
__global__ __launch_bounds__(256) void k_gemm_G(
    const float* __restrict__ h, const uint4* __restrict__ Bf,
    u16* __restrict__ Gb, int N, int p) {
  int wave = threadIdx.x >> 6;
  int lane = threadIdx.x & 63;
  int jt = blockIdx.y * 4 + wave;   // [0,64)
  int n0 = blockIdx.x * 16;
  int row = lane & 15;
  int kg = lane >> 4;

  int nr = n0 + row; if (nr > N - 1) nr = N - 1;
  const float* hr = h + (size_t)nr * HD + kg * 8;
  float4 f0 = *(const float4*)hr;
  float4 f1 = *(const float4*)(hr + 4);
  frag16 a;
  a.s[0] = f2bf(f0.x); a.s[1] = f2bf(f0.y); a.s[2] = f2bf(f0.z); a.s[3] = f2bf(f0.w);
  a.s[4] = f2bf(f1.x); a.s[5] = f2bf(f1.y); a.s[6] = f2bf(f1.z); a.s[7] = f2bf(f1.w);

  frag16 b; b.v = Bf[(p * 64 + jt) * 64 + lane];

  f32x4 acc = {0.f, 0.f, 0.f, 0.f};
  acc = __builtin_amdgcn_mfma_f32_16x16x32_bf16(a.b, b.b, acc, 0, 0, 0);

  int j2 = jt * 16 + row;
#pragma unroll
  for (int r = 0; r < 4; r++) {
    int n = n0 + kg * 4 + r;
    if (n < N) Gb[(size_t)n * 1024 + j2] = f2bf(acc[r]);
  }
}

// ---------------- msg pass p: 16 lanes per sorted edge; atomic-free scatter
// msgbuf[dstpos[e]*32 + p*16 + o_l] = hb[src][o] + sum_k ee[e][k]*Gb[src][o_l*64+k]
__global__ __launch_bounds__(256) void k_msg(
    const u16* __restrict__ Gb, const float* __restrict__ hbbuf,
    const u16* __restrict__ ee, const int* __restrict__ se_src,
    const int* __restrict__ dstpos, float* __restrict__ msgbuf, int E, int p) {
  int t = blockIdx.x * blockDim.x + threadIdx.x;
  int e = t >> 4;
  int o_l = t & 15;
  if (e >= E) return;
  int src = se_src[e];

  float acc = hbbuf[(size_t)src * HD + p * 16 + o_l];

  const uint4* ep = (const uint4*)(ee + (size_t)e * 64);
  const uint4* gp = (const uint4*)(Gb + ((size_t)src * 16 + o_l) * 64);
  frag16 eu[8], gu[8];
#pragma unroll
  for (int q = 0; q < 8; q++) { eu[q].v = ep[q]; gu[q].v = gp[q]; }
#pragma unroll
  for (int k = 0; k < 64; k++) {
    acc = fmaf(bf2f(eu[k >> 3].s[k & 7]), bf2f(gu[k >> 3].s[k & 7]), acc);
  }
  msgbuf[(size_t)dstpos[e] * HD + p * 16 + o_l] = acc;
}

// ---------------- fused: segment-sum agg + node update + next hb
__global__ __launch_bounds__(256) void k_aggupd(
    const float* __restrict__ msgbuf, const int* __restrict__ rowptrD,
    const float* __restrict__ h, const float* __restrict__ root,
    const float* __restrict__ bias, const float* __restrict__ bm2,
    float* __restrict__ hn, float* __restrict__ hbbuf, int N) {
  int t = blockIdx.x * blockDim.x + threadIdx.x;
  int n = t >> 5, o = t & 31;
  if (n >= N) return;
  int jb = rowptrD[n], je = rowptrD[n + 1];
  float s = 0.f;
  for (int j = jb; j < je; j++) s += msgbuf[(size_t)j * HD + o];

  float hv = h[(size_t)n * HD + o];
  float acc = bias[o] + s;
#pragma unroll
  for (int k = 0; k < 32; k++)
    acc = fmaf(__shfl(hv, k, 32), root[k * HD + o], acc);
  hn[(size_t)n * HD + o] = acc;

  float hb = 0.f;
#pragma unroll
  for (int k = 0; k < 32; k++)
    hb = fmaf(__shfl(acc, k, 32), bm2[k * 32 + o], hb);
  hbbuf[(size_t)n * HD + o] = hb;
}

// ---------------- readout
__global__ __launch_bounds__(256) void k_readout(
    const float* __restrict__ h, const float* __restrict__ x,
    const float* __restrict__ Wi0, const float* __restrict__ bi0,
    const float* __restrict__ Wi1, const float* __restrict__ bi1,
    const float* __restrict__ Wj0, const float* __restrict__ bj0,
    const float* __restrict__ Wj1, const float* __restrict__ bj1,
    float* __restrict__ partial, int N) {
  int wid = threadIdx.x >> 6;
  int lane = threadIdx.x & 63;
  int n = blockIdx.x * 4 + wid;
  __shared__ float sred[4];
  float contrib = 0.f;
  if (n < N) {
    float uv;
    if (lane < 32) uv = h[(size_t)n * HD + lane];
    else if (lane < 48) uv = x[(size_t)n * FN + lane - 32];
    else uv = 0.f;

    float g1a = bi0[lane], g1b = bi0[lane + 64];
#pragma unroll
    for (int k = 0; k < 64; k++) {
      float u = __shfl(uv, k, 64);
      g1a = fmaf(u, Wi0[k * 128 + lane], g1a);
      g1b = fmaf(u, Wi0[k * 128 + lane + 64], g1b);
    }
    g1a = fmaxf(g1a, 0.f); g1b = fmaxf(g1b, 0.f);
    float gp = g1a * Wi1[lane] + g1b * Wi1[lane + 64];

    float v1a = bj0[lane], v1b = bj0[lane + 64];
#pragma unroll
    for (int k = 0; k < 32; k++) {
      float hk = __shfl(uv, k, 64);
      v1a = fmaf(hk, Wj0[k * 128 + lane], v1a);
      v1b = fmaf(hk, Wj0[k * 128 + lane + 64], v1b);
    }
    v1a = fmaxf(v1a, 0.f); v1b = fmaxf(v1b, 0.f);
    float vp = v1a * Wj1[lane] + v1b * Wj1[lane + 64];

#pragma unroll
    for (int s = 32; s; s >>= 1) {
      gp += __shfl_xor(gp, s, 64);
      vp += __shfl_xor(vp, s, 64);
    }
    float gate = 1.f / (1.f + __expf(-(gp + bi1[0])));
    float val = vp + bj1[0];
    contrib = gate * val;
  }
  if (lane == 0) sred[wid] = contrib;
  __syncthreads();
  if (threadIdx.x == 0) partial[blockIdx.x] = sred[0] + sred[1] + sred[2] + sred[3];
}

__global__ void k_final(const float* __restrict__ partial, float* __restrict__ out, int P) {
  __shared__ float sm[256];
  float s = 0.f;
  for (int i = threadIdx.x; i < P; i += 256) s += partial[i];
  sm[threadIdx.x] = s;
  __syncthreads();
  for (int st = 128; st; st >>= 1) {
    if ((int)threadIdx.x < st) sm[threadIdx.x] += sm[threadIdx.x + st];
    __syncthreads();
  }
  if (threadIdx.x == 0) out[0] = sm[0];
}

extern "C" void kernel_launch(void* const* d_in, const int* in_sizes, int n_in,
                              void* d_out, int out_size, void* d_ws, size_t ws_size,
                              hipStream_t stream) {
  const float* x    = (const float*)d_in[0];
  const int*   eidx = (const int*)d_in[1];
  const float* ea   = (const float*)d_in[2];
  const float* Wm0  = (const float*)d_in[3];
  const float* bm0  = (const float*)d_in[4];
  const float* Wm1  = (const float*)d_in[5];
  const float* bm1  = (const float*)d_in[6];
  const float* Wm2  = (const float*)d_in[7];
  const float* bm2  = (const float*)d_in[8];
  const float* root = (const float*)d_in[9];
  const float* bias = (const float*)d_in[10];
  const float* Wi0  = (const float*)d_in[11];
  const float* bi0  = (const float*)d_in[12];
  const float* Wi1  = (const float*)d_in[13];
  const float* bi1  = (const float*)d_in[14];
  const float* Wj0  = (const float*)d_in[15];
  const float* bj0  = (const float*)d_in[16];
  const float* Wj1  = (const float*)d_in[17];
  const float* bj1  = (const float*)d_in[18];

  int N = in_sizes[0] / FN;
  int E = in_sizes[1] / 2;
  int nb = (N + 3) / 4;

  auto al = [](size_t b) { return (b + 255) & ~(size_t)255; };
  size_t need = al((size_t)N * 1024 * 2)       // Gb
              + al((size_t)E * 64 * 2)         // ee
              + al((size_t)E * HD * 4)         // msgbuf
              + al(128 * 64 * sizeof(uint4))   // Bf
              + 3 * al((size_t)N * HD * 4)     // hA hB hbbuf
              + 2 * al((size_t)N * 4)          // cntS cntD
              + 3 * al(((size_t)N + 1) * 4)    // ptrS rowptrD ptrD
              + 4 * al((size_t)E * 4)          // se_src se_dst invp dstpos
              + al((size_t)nb * 4);
  if (need > ws_size) return;  // beacon: workspace too small

  char* ws = (char*)d_ws;
  size_t off = 0;
  auto alloc = [&](size_t bytes) { void* p = ws + off; off += al(bytes); return p; };
  u16*   Gb      = (u16*)alloc((size_t)N * 1024 * 2);    // 102.4 MB
  u16*   ee      = (u16*)alloc((size_t)E * 64 * 2);      // 51.2 MB
  float* msgbuf  = (float*)alloc((size_t)E * HD * 4);    // 51.2 MB
  uint4* Bf      = (uint4*)alloc(128 * 64 * sizeof(uint4));
  float* hA      = (float*)alloc((size_t)N * HD * 4);
  float* hB      = (float*)alloc((size_t)N * HD * 4);
  float* hbbuf   = (float*)alloc((size_t)N * HD * 4);
  int*   cntS    = (int*)alloc((size_t)N * 4);
  int*   cntD    = (int*)alloc((size_t)N * 4);
  int*   ptrS    = (int*)alloc(((size_t)N + 1) * 4);
  int*   rowptrD = (int*)alloc(((size_t)N + 1) * 4);
  int*   ptrD    = (int*)alloc(((size_t)N + 1) * 4);
  int*   se_src  = (int*)alloc((size_t)E * 4);
  int*   se_dst  = (int*)alloc((size_t)E * 4);
  int*   invp    = (int*)alloc((size_t)E * 4);
  int*   dstpos  = (int*)alloc((size_t)E * 4);
  float* partial = (float*)alloc((size_t)nb * 4);

  int mt = (N + 15) / 16;
  int ng = (N * HD + 255) / 256;
  int eg = (E + 255) / 256;

  // ---- one-time: src-sort + dst-rank ----
  int zn = (int)(((char*)cntD - (char*)cntS) / 4) + N;  // covers cntS..cntD incl padding
  hipLaunchKernelGGL(k_zero_i, dim3((zn + 255) / 256), dim3(256), 0, stream, cntS, zn);
  hipLaunchKernelGGL(k_hist2, dim3(eg), dim3(256), 0, stream, eidx, cntS, cntD, E);
  hipLaunchKernelGGL(k_scan, dim3(1), dim3(1024), 0, stream, cntS, ptrS, (int*)nullptr, N);
  hipLaunchKernelGGL(k_scan, dim3(1), dim3(1024), 0, stream, cntD, rowptrD, ptrD, N);
  hipLaunchKernelGGL(k_scatter_src, dim3(eg), dim3(256), 0, stream,
                     eidx, ptrS, se_src, se_dst, invp, E);
  hipLaunchKernelGGL(k_dstpos, dim3(eg), dim3(256), 0, stream, se_dst, ptrD, dstpos, E);

  hipLaunchKernelGGL(k_prep_bf, dim3(128), dim3(64), 0, stream, Wm2, Bf);
  hipLaunchKernelGGL(k_init_h, dim3(ng), dim3(256), 0, stream, x, bm2, hA, hbbuf, N);
  hipLaunchKernelGGL(k_edge_mlp, dim3(eg), dim3(256), 0, stream,
                     ea, Wm0, bm0, Wm1, bm1, invp, ee, E);

  float* hc = hA; float* hn = hB;
  for (int it = 0; it < N_UPDATE; it++) {
    for (int p = 0; p < 2; p++) {
      hipLaunchKernelGGL(k_gemm_G, dim3(mt, 16), dim3(256), 0, stream, hc, Bf, Gb, N, p);
      hipLaunchKernelGGL(k_msg, dim3(((size_t)E * 16 + 255) / 256), dim3(256), 0, stream,
                         Gb, hbbuf, ee, se_src, dstpos, msgbuf, E, p);
    }
    hipLaunchKernelGGL(k_aggupd, dim3(ng), dim3(256), 0, stream,
                       msgbuf, rowptrD, hc, root, bias, bm2, hn, hbbuf, N);
    float* tmp = hc; hc = hn; hn = tmp;
  }

  hipLaunchKernelGGL(k_readout, dim3(nb), dim3(256), 0, stream,
                     hc, x, Wi0, bi0, Wi1, bi1, Wj0, bj0, Wj1, bj1, partial, N);
  hipLaunchKernelGGL(k_final, dim3(1), dim3(256), 0, stream, partial, (float*)d_out, nb);
}

// Round 7
// 1455.304 us; speedup vs baseline: 1.1588x; 1.1588x over previous
//
#include <hip/hip_runtime.h>
#include <stdint.h>

#define N_UPDATE 3
#define HD 32
#define FN 16

typedef unsigned short u16;
typedef __bf16 bf16x8 __attribute__((ext_vector_type(8)));
typedef float f32x4 __attribute__((ext_vector_type(4)));

__device__ __forceinline__ float bf2f(u16 u) {
  union { uint32_t i; float f; } v; v.i = ((uint32_t)u) << 16; return v.f;
}
__device__ __forceinline__ u16 f2bf(float f) {
  union { uint32_t i; float f; } v; v.f = f;
  uint32_t x = v.i;
  return (u16)((x + 0x7fffu + ((x >> 16) & 1u)) >> 16);  // RNE
}

union frag16 { uint4 v; bf16x8 b; u16 s[8]; };

__global__ void k_zero_i(int* __restrict__ p, int n) {
  int i = blockIdx.x * blockDim.x + threadIdx.x;
  if (i < n) p[i] = 0;
}

// ---------------- both histograms in one pass
__global__ void k_hist2(const int* __restrict__ eidx, int* __restrict__ cntS,
                        int* __restrict__ cntD, int E) {
  int e = blockIdx.x * blockDim.x + threadIdx.x;
  if (e >= E) return;
  int2 sd = ((const int2*)eidx)[e];
  atomicAdd(&cntS[sd.x], 1);
  atomicAdd(&cntD[sd.y], 1);
}

// ---------------- single-block exclusive scan; writes out1[0..N] (and out2 if non-null)
__global__ __launch_bounds__(1024) void k_scan(const int* __restrict__ cnt,
                                               int* __restrict__ out1,
                                               int* __restrict__ out2, int N) {
  __shared__ int sums[1024];
  int chunk = (N + 1023) / 1024;
  int beg = threadIdx.x * chunk;
  int end = beg + chunk; if (end > N) end = N;
  if (beg > N) beg = N;
  int s = 0;
  for (int i = beg; i < end; i++) s += cnt[i];
  sums[threadIdx.x] = s;
  __syncthreads();
  for (int off = 1; off < 1024; off <<= 1) {
    int v = (threadIdx.x >= off) ? sums[threadIdx.x - off] : 0;
    __syncthreads();
    sums[threadIdx.x] += v;
    __syncthreads();
  }
  int run = (threadIdx.x == 0) ? 0 : sums[threadIdx.x - 1];
  for (int i = beg; i < end; i++) {
    out1[i] = run;
    if (out2) out2[i] = run;
    run += cnt[i];
  }
  if (end == N) {
    out1[N] = run;
    if (out2) out2[N] = run;
  }
}

// ---------------- scatter into src-sorted order + dst-order rank, packed
__global__ void k_scatter(const int* __restrict__ eidx, int* __restrict__ ptrS,
                          int* __restrict__ ptrD, int2* __restrict__ spd,
                          int* __restrict__ invp, int E) {
  int e = blockIdx.x * blockDim.x + threadIdx.x;
  if (e >= E) return;
  int2 sd = ((const int2*)eidx)[e];
  int pos = atomicAdd(&ptrS[sd.x], 1);
  int dpos = atomicAdd(&ptrD[sd.y], 1);
  spd[pos] = make_int2(sd.x, dpos);
  invp[e] = pos;
}

// ---------------- Bf[t][lane]: MFMA B-fragments, 128 tiles (2 passes x 64).
// pass p, tile t2, col c: j2=t2*16+c, o_l=j2>>6, k=j2&63, o=p*16+o_l
// B[h][j2] = Wm2[k*1024 + h*32 + o]
__global__ void k_prep_bf(const float* __restrict__ Wm2, uint4* __restrict__ Bf) {
  int t = blockIdx.x;       // 128
  int lane = threadIdx.x;   // 64
  int col = lane & 15;
  int hg = lane >> 4;
  int p = t >> 6;
  int t2 = t & 63;
  int j2 = t2 * 16 + col;
  int o = p * 16 + (j2 >> 6);
  int k = j2 & 63;
  frag16 f;
#pragma unroll
  for (int jj = 0; jj < 8; jj++) {
    int h = hg * 8 + jj;
    f.s[jj] = f2bf(Wm2[k * 1024 + h * 32 + o]);
  }
  Bf[t * 64 + lane] = f.v;
}

// ---------------- h0 init + hb = h0 @ bm2
__global__ void k_init_h(const float* __restrict__ x, const float* __restrict__ bm2,
                         float* __restrict__ h, float* __restrict__ hbbuf, int N) {
  int idx = blockIdx.x * blockDim.x + threadIdx.x;
  if (idx >= N * HD) return;
  int n = idx >> 5, o = idx & 31;
  float v = (o < FN) ? x[n * FN + o] : 0.f;
  h[idx] = v;
  float hb = 0.f;
#pragma unroll
  for (int k = 0; k < 32; k++)
    hb = fmaf(__shfl(v, k, 32), bm2[k * 32 + o], hb);
  hbbuf[idx] = hb;
}

// ---------------- edge MLP -> ee bf16 [E][64], written at sorted position invp[e]
__global__ __launch_bounds__(256) void k_edge_mlp(
    const float* __restrict__ ea,
    const float* __restrict__ Wm0, const float* __restrict__ bm0,
    const float* __restrict__ Wm1, const float* __restrict__ bm1,
    const int* __restrict__ invp, u16* __restrict__ ee, int E) {
  int e = blockIdx.x * blockDim.x + threadIdx.x;
  if (e >= E) return;
  float a[16];
  {
    const float4* p = (const float4*)(ea + (size_t)e * 16);
    float4 v0 = p[0], v1 = p[1], v2 = p[2], v3 = p[3];
    a[0]=v0.x; a[1]=v0.y; a[2]=v0.z; a[3]=v0.w;
    a[4]=v1.x; a[5]=v1.y; a[6]=v1.z; a[7]=v1.w;
    a[8]=v2.x; a[9]=v2.y; a[10]=v2.z; a[11]=v2.w;
    a[12]=v3.x; a[13]=v3.y; a[14]=v3.z; a[15]=v3.w;
  }
  float t0[64];
#pragma unroll
  for (int j = 0; j < 64; j++) t0[j] = bm0[j];
#pragma unroll
  for (int k = 0; k < 16; k++) {
    float av = a[k];
#pragma unroll
    for (int j = 0; j < 64; j++) t0[j] = fmaf(av, Wm0[k * 64 + j], t0[j]);
  }
#pragma unroll
  for (int j = 0; j < 64; j++) t0[j] = fmaxf(t0[j], 0.f);

  u16* dst = ee + (size_t)invp[e] * 64;
#pragma unroll
  for (int half = 0; half < 2; half++) {
    float t1[32];
#pragma unroll
    for (int j = 0; j < 32; j++) t1[j] = bm1[half * 32 + j];
#pragma unroll
    for (int k = 0; k < 64; k++) {
      float tv = t0[k];
#pragma unroll
      for (int j = 0; j < 32; j++) t1[j] = fmaf(tv, Wm1[k * 64 + half * 32 + j], t1[j]);
    }
    unsigned int out[16];
#pragma unroll
    for (int j = 0; j < 16; j++) {
      u16 lo = f2bf(fmaxf(t1[2 * j], 0.f));
      u16 hi = f2bf(fmaxf(t1[2 * j + 1], 0.f));
      out[j] = (unsigned int)lo | ((unsigned int)hi << 16);
    }
    uint4* op = (uint4*)(dst + half * 32);
#pragma unroll
    for (int q = 0; q < 4; q++) {
      uint4 w; w.x = out[q*4+0]; w.y = out[q*4+1]; w.z = out[q*4+2]; w.w = out[q*4+3];
      op[q] = w;
    }
  }
}

// ---------------- G GEMM pass p. One wave handles 16 column-tiles (A loaded once).
// Swizzled store: Gb[n][q*128 + o_l*8 + rem], q=k>>3, rem=k&7  (o = p*16+o_l, k in [0,64))
__global__ __launch_bounds__(256) void k_gemm_G(
    const float* __restrict__ h, const uint4* __restrict__ Bf,
    u16* __restrict__ Gb, int N, int p) {
  int wave = threadIdx.x >> 6;
  int lane = threadIdx.x & 63;
  int n0 = blockIdx.x * 16;
  int row = lane & 15;
  int kg = lane >> 4;

  int nr = n0 + row; if (nr > N - 1) nr = N - 1;
  const float* hr = h + (size_t)nr * HD + kg * 8;
  float4 f0 = *(const float4*)hr;
  float4 f1 = *(const float4*)(hr + 4);
  frag16 a;
  a.s[0] = f2bf(f0.x); a.s[1] = f2bf(f0.y); a.s[2] = f2bf(f0.z); a.s[3] = f2bf(f0.w);
  a.s[4] = f2bf(f1.x); a.s[5] = f2bf(f1.y); a.s[6] = f2bf(f1.z); a.s[7] = f2bf(f1.w);

#pragma unroll
  for (int i = 0; i < 16; i++) {
    int jt = wave * 16 + i;   // [0,64)
    frag16 b; b.v = Bf[(p * 64 + jt) * 64 + lane];
    f32x4 acc = {0.f, 0.f, 0.f, 0.f};
    acc = __builtin_amdgcn_mfma_f32_16x16x32_bf16(a.b, b.b, acc, 0, 0, 0);

    int o_l = jt >> 2;
    int k = (jt & 3) * 16 + row;          // column's k index
    int idx = (k >> 3) * 128 + o_l * 8 + (k & 7);
#pragma unroll
    for (int r = 0; r < 4; r++) {
      int n = n0 + kg * 4 + r;
      if (n < N) Gb[(size_t)n * 1024 + idx] = f2bf(acc[r]);
    }
  }
}

// ---------------- msg pass p: 16 lanes per sorted edge; contiguous Gb loads
// msgbuf[dpos*32 + p*16 + o_l] = hb[src][o] + sum_k ee[e][k]*G[src][o][k]
__global__ __launch_bounds__(256) void k_msg(
    const u16* __restrict__ Gb, const float* __restrict__ hbbuf,
    const u16* __restrict__ ee, const int2* __restrict__ spd,
    float* __restrict__ msgbuf, int E, int p) {
  int t = blockIdx.x * blockDim.x + threadIdx.x;
  int e = t >> 4;
  int o_l = t & 15;
  if (e >= E) return;
  int2 sp = spd[e];   // (src, dpos)

  float acc = hbbuf[(size_t)sp.x * HD + p * 16 + o_l];

  const uint4* ep = (const uint4*)(ee + (size_t)e * 64);
  const uint4* gp = (const uint4*)(Gb + (size_t)sp.x * 1024);
  frag16 eu[8], gu[8];
#pragma unroll
  for (int q = 0; q < 8; q++) {
    eu[q].v = ep[q];
    gu[q].v = gp[q * 16 + o_l];   // (q*128 + o_l*8) u16 / 8 per uint4
  }
#pragma unroll
  for (int k = 0; k < 64; k++) {
    acc = fmaf(bf2f(eu[k >> 3].s[k & 7]), bf2f(gu[k >> 3].s[k & 7]), acc);
  }
  msgbuf[(size_t)sp.y * HD + p * 16 + o_l] = acc;
}

// ---------------- fused: segment-sum agg + node update + next hb
__global__ __launch_bounds__(256) void k_aggupd(
    const float* __restrict__ msgbuf, const int* __restrict__ rowptrD,
    const float* __restrict__ h, const float* __restrict__ root,
    const float* __restrict__ bias, const float* __restrict__ bm2,
    float* __restrict__ hn, float* __restrict__ hbbuf, int N) {
  int t = blockIdx.x * blockDim.x + threadIdx.x;
  int n = t >> 5, o = t & 31;
  if (n >= N) return;
  int jb = rowptrD[n], je = rowptrD[n + 1];
  float s = 0.f;
  for (int j = jb; j < je; j++) s += msgbuf[(size_t)j * HD + o];

  float hv = h[(size_t)n * HD + o];
  float acc = bias[o] + s;
#pragma unroll
  for (int k = 0; k < 32; k++)
    acc = fmaf(__shfl(hv, k, 32), root[k * HD + o], acc);
  hn[(size_t)n * HD + o] = acc;

  float hb = 0.f;
#pragma unroll
  for (int k = 0; k < 32; k++)
    hb = fmaf(__shfl(acc, k, 32), bm2[k * 32 + o], hb);
  hbbuf[(size_t)n * HD + o] = hb;
}

// ---------------- readout
__global__ __launch_bounds__(256) void k_readout(
    const float* __restrict__ h, const float* __restrict__ x,
    const float* __restrict__ Wi0, const float* __restrict__ bi0,
    const float* __restrict__ Wi1, const float* __restrict__ bi1,
    const float* __restrict__ Wj0, const float* __restrict__ bj0,
    const float* __restrict__ Wj1, const float* __restrict__ bj1,
    float* __restrict__ partial, int N) {
  int wid = threadIdx.x >> 6;
  int lane = threadIdx.x & 63;
  int n = blockIdx.x * 4 + wid;
  __shared__ float sred[4];
  float contrib = 0.f;
  if (n < N) {
    float uv;
    if (lane < 32) uv = h[(size_t)n * HD + lane];
    else if (lane < 48) uv = x[(size_t)n * FN + lane - 32];
    else uv = 0.f;

    float g1a = bi0[lane], g1b = bi0[lane + 64];
#pragma unroll
    for (int k = 0; k < 64; k++) {
      float u = __shfl(uv, k, 64);
      g1a = fmaf(u, Wi0[k * 128 + lane], g1a);
      g1b = fmaf(u, Wi0[k * 128 + lane + 64], g1b);
    }
    g1a = fmaxf(g1a, 0.f); g1b = fmaxf(g1b, 0.f);
    float gp = g1a * Wi1[lane] + g1b * Wi1[lane + 64];

    float v1a = bj0[lane], v1b = bj0[lane + 64];
#pragma unroll
    for (int k = 0; k < 32; k++) {
      float hk = __shfl(uv, k, 64);
      v1a = fmaf(hk, Wj0[k * 128 + lane], v1a);
      v1b = fmaf(hk, Wj0[k * 128 + lane + 64], v1b);
    }
    v1a = fmaxf(v1a, 0.f); v1b = fmaxf(v1b, 0.f);
    float vp = v1a * Wj1[lane] + v1b * Wj1[lane + 64];

#pragma unroll
    for (int s = 32; s; s >>= 1) {
      gp += __shfl_xor(gp, s, 64);
      vp += __shfl_xor(vp, s, 64);
    }
    float gate = 1.f / (1.f + __expf(-(gp + bi1[0])));
    float val = vp + bj1[0];
    contrib = gate * val;
  }
  if (lane == 0) sred[wid] = contrib;
  __syncthreads();
  if (threadIdx.x == 0) partial[blockIdx.x] = sred[0] + sred[1] + sred[2] + sred[3];
}

__global__ void k_final(const float* __restrict__ partial, float* __restrict__ out, int P) {
  __shared__ float sm[256];
  float s = 0.f;
  for (int i = threadIdx.x; i < P; i += 256) s += partial[i];
  sm[threadIdx.x] = s;
  __syncthreads();
  for (int st = 128; st; st >>= 1) {
    if ((int)threadIdx.x < st) sm[threadIdx.x] += sm[threadIdx.x + st];
    __syncthreads();
  }
  if (threadIdx.x == 0) out[0] = sm[0];
}

extern "C" void kernel_launch(void* const* d_in, const int* in_sizes, int n_in,
                              void* d_out, int out_size, void* d_ws, size_t ws_size,
                              hipStream_t stream) {
  const float* x    = (const float*)d_in[0];
  const int*   eidx = (const int*)d_in[1];
  const float* ea   = (const float*)d_in[2];
  const float* Wm0  = (const float*)d_in[3];
  const float* bm0  = (const float*)d_in[4];
  const float* Wm1  = (const float*)d_in[5];
  const float* bm1  = (const float*)d_in[6];
  const float* Wm2  = (const float*)d_in[7];
  const float* bm2  = (const float*)d_in[8];
  const float* root = (const float*)d_in[9];
  const float* bias = (const float*)d_in[10];
  const float* Wi0  = (const float*)d_in[11];
  const float* bi0  = (const float*)d_in[12];
  const float* Wi1  = (const float*)d_in[13];
  const float* bi1  = (const float*)d_in[14];
  const float* Wj0  = (const float*)d_in[15];
  const float* bj0  = (const float*)d_in[16];
  const float* Wj1  = (const float*)d_in[17];
  const float* bj1  = (const float*)d_in[18];

  int N = in_sizes[0] / FN;
  int E = in_sizes[1] / 2;
  int nb = (N + 3) / 4;

  auto al = [](size_t b) { return (b + 255) & ~(size_t)255; };
  size_t need = al((size_t)N * 1024 * 2)       // Gb
              + al((size_t)E * 64 * 2)         // ee
              + al((size_t)E * HD * 4)         // msgbuf
              + al(128 * 64 * sizeof(uint4))   // Bf
              + 3 * al((size_t)N * HD * 4)     // hA hB hbbuf
              + 2 * al((size_t)N * 4)          // cntS cntD
              + 3 * al(((size_t)N + 1) * 4)    // ptrS rowptrD ptrD
              + al((size_t)E * 8)              // spd
              + al((size_t)E * 4)              // invp
              + al((size_t)nb * 4);
  if (need > ws_size) return;  // beacon: workspace too small

  char* ws = (char*)d_ws;
  size_t off = 0;
  auto alloc = [&](size_t bytes) { void* p = ws + off; off += al(bytes); return p; };
  u16*   Gb      = (u16*)alloc((size_t)N * 1024 * 2);    // 102.4 MB
  u16*   ee      = (u16*)alloc((size_t)E * 64 * 2);      // 51.2 MB
  float* msgbuf  = (float*)alloc((size_t)E * HD * 4);    // 51.2 MB
  uint4* Bf      = (uint4*)alloc(128 * 64 * sizeof(uint4));
  float* hA      = (float*)alloc((size_t)N * HD * 4);
  float* hB      = (float*)alloc((size_t)N * HD * 4);
  float* hbbuf   = (float*)alloc((size_t)N * HD * 4);
  int*   cntS    = (int*)alloc((size_t)N * 4);
  int*   cntD    = (int*)alloc((size_t)N * 4);
  int*   ptrS    = (int*)alloc(((size_t)N + 1) * 4);
  int*   rowptrD = (int*)alloc(((size_t)N + 1) * 4);
  int*   ptrD    = (int*)alloc(((size_t)N + 1) * 4);
  int2*  spd     = (int2*)alloc((size_t)E * 8);
  int*   invp    = (int*)alloc((size_t)E * 4);
  float* partial = (float*)alloc((size_t)nb * 4);

  int mt = (N + 15) / 16;
  int ng = (N * HD + 255) / 256;
  int eg = (E + 255) / 256;

  // ---- one-time: src-sort + dst-rank ----
  int zn = (int)(((char*)cntD - (char*)cntS) / 4) + N;  // covers cntS..cntD incl padding
  hipLaunchKernelGGL(k_zero_i, dim3((zn + 255) / 256), dim3(256), 0, stream, cntS, zn);
  hipLaunchKernelGGL(k_hist2, dim3(eg), dim3(256), 0, stream, eidx, cntS, cntD, E);
  hipLaunchKernelGGL(k_scan, dim3(1), dim3(1024), 0, stream, cntS, ptrS, (int*)nullptr, N);
  hipLaunchKernelGGL(k_scan, dim3(1), dim3(1024), 0, stream, cntD, rowptrD, ptrD, N);
  hipLaunchKernelGGL(k_scatter, dim3(eg), dim3(256), 0, stream,
                     eidx, ptrS, ptrD, spd, invp, E);

  hipLaunchKernelGGL(k_prep_bf, dim3(128), dim3(64), 0, stream, Wm2, Bf);
  hipLaunchKernelGGL(k_init_h, dim3(ng), dim3(256), 0, stream, x, bm2, hA, hbbuf, N);
  hipLaunchKernelGGL(k_edge_mlp, dim3(eg), dim3(256), 0, stream,
                     ea, Wm0, bm0, Wm1, bm1, invp, ee, E);

  float* hc = hA; float* hn = hB;
  for (int it = 0; it < N_UPDATE; it++) {
    for (int p = 0; p < 2; p++) {
      hipLaunchKernelGGL(k_gemm_G, dim3(mt), dim3(256), 0, stream, hc, Bf, Gb, N, p);
      hipLaunchKernelGGL(k_msg, dim3(((size_t)E * 16 + 255) / 256), dim3(256), 0, stream,
                         Gb, hbbuf, ee, spd, msgbuf, E, p);
    }
    hipLaunchKernelGGL(k_aggupd, dim3(ng), dim3(256), 0, stream,
                       msgbuf, rowptrD, hc, root, bias, bm2, hn, hbbuf, N);
    float* tmp = hc; hc = hn; hn = tmp;
  }

  hipLaunchKernelGGL(k_readout, dim3(nb), dim3(256), 0, stream,
                     hc, x, Wi0, bi0, Wi1, bi1, Wj0, bj0, Wj1, bj1, partial, N);
  hipLaunchKernelGGL(k_final, dim3(1), dim3(256), 0, stream, partial, (float*)d_out, nb);
}